// Round 7
// baseline (2923.028 us; speedup 1.0000x reference)
//
#include <hip/hip_runtime.h>
#include <math.h>

#define D 256
#define K 1024
#define N_PTS 65536            // 64 * 32 * 32
#define BETA 0.25f
#define ORTHO_L 10.0f

#define OUT_ELEMS 16777216     // 64*256*32*32
#define LOSS_OFF 16777216
#define IDX_OFF  16777217

// ws float layout
#define WS_SSE_VQ    0
#define WS_SSE_ORTHO 1
#define WS_MAXN      2            // max ||e_k|| as float bits (atomicMax on uint)
#define WS_B         4            // 1024 floats: ||e_k||^2
#define WS_NORM      (4 + 1024)   // 1024 floats: ||e_k||

typedef short bf16x8 __attribute__((ext_vector_type(8)));
typedef float f32x4  __attribute__((ext_vector_type(4)));

union ABu { bf16x8 v; unsigned short h[8]; uint4 q; };

__device__ __forceinline__ unsigned short f2bf(float v) {
    unsigned u = __float_as_uint(v);
    unsigned r = (u + 0x7FFFu + ((u >> 16) & 1u)) >> 16;   // RNE
    return (unsigned short)r;
}
// monotone float<->uint keys for atomicMin over possibly-negative floats
__device__ __forceinline__ unsigned fenc(float f) {
    unsigned b = __float_as_uint(f);
    return (b & 0x80000000u) ? ~b : (b | 0x80000000u);
}
__device__ __forceinline__ float fdec(unsigned e) {
    unsigned b = (e & 0x80000000u) ? (e & 0x7FFFFFFFu) : ~e;
    return __uint_as_float(b);
}

// ---------------- kernel 1: per-code squared norms (+ max norm) ----------------
__global__ __launch_bounds__(64) void codes_kernel(const float* __restrict__ w,
                                                   float* __restrict__ ws) {
    int k = blockIdx.x;
    int lane = threadIdx.x;                       // 0..63
    float4 v = *(const float4*)(w + (size_t)k * D + lane * 4);
    float s = v.x * v.x + v.y * v.y + v.z * v.z + v.w * v.w;
    for (int m = 32; m; m >>= 1) s += __shfl_xor(s, m, 64);
    if (lane == 0) {
        float nrm = sqrtf(s);
        ws[WS_B + k] = s;
        ws[WS_NORM + k] = nrm;
        atomicMax((unsigned*)(ws + WS_MAXN), __float_as_uint(nrm));  // positive floats
    }
}

// ---------------- kernel 2: MFMA filter + exact-fp32 rescue argmin ----------------
// Block: 32 pts x all 1024 codes, 256 threads (4 waves: wr=wv>>1 pt-half, wc=wv&1 code-half).
// Phase A: s~ = B_k - 2*dot(bf16(x),bf16(w)) via mfma_f32_16x16x32_bf16, running min +
//          candidate buffer (margin M >= 2*eps + 2*ulp, eps = 2^-8 ||x|| ||w|| rigorous).
// Phase B: layout self-check (tile(0,0) 16x16 vs serial fp32) -> block fallback if bad.
// Phase C: exact R1-replica distance (fmaf ascending d, fl(A+B)-fl(2C), first-min) on
//          candidates only -> idx bitwise identical to R1's passing kernel.
#define MT 32

__global__ __launch_bounds__(256) void argmin_kernel(const float* __restrict__ x,
                                                     const float* __restrict__ w,
                                                     const float* __restrict__ wsb,
                                                     float* __restrict__ out_idx) {
    __shared__ float Xs[MT][264];     // fp32 X, pt-major, padded (33.8 KB)
    __shared__ uint4 Wc[512];         // bf16 W chunk [128 codes][32 d] as 16B granules (8 KB)
    __shared__ float Bs[K];           // 4 KB
    __shared__ float Apart[8][MT];
    __shared__ float Ash[MT];
    __shared__ float Mls[MT];
    __shared__ unsigned runmin[MT];
    __shared__ int cnt[MT];
    __shared__ int cand[MT][16];
    __shared__ float chk[16][16];
    __shared__ int badflag;

    int tid = threadIdx.x;
    int l   = tid & 63;
    int wv  = tid >> 6;
    int wr  = wv >> 1;
    int wc  = wv & 1;

    int n0 = blockIdx.x * MT;
    int b  = n0 >> 10;
    int hw0 = n0 & 1023;

    // ---- stage X fp32 (pt-major) ----
    const float* xb = x + (size_t)b * (D * 1024) + hw0;
    {
        int p = tid & 31, cq = tid >> 5;
        for (int c0 = 0; c0 < D; c0 += 8) {
            int c = c0 + cq;
            Xs[p][c] = xb[(size_t)c * 1024 + p];
        }
    }
    *(float4*)&Bs[tid * 4] = *(const float4*)&wsb[WS_B + tid * 4];
    if (tid < MT) { runmin[tid] = 0xFFFFFFFFu; cnt[tid] = 0; }
    if (tid == 0) badflag = 0;
    __syncthreads();

    // ---- A_n exact (same tree as R1: 32-chunk sums, then q-ascending) ----
    {
        int p = tid & 31, q = tid >> 5;
        float s = 0.f;
        #pragma unroll
        for (int dd = 0; dd < 32; ++dd) { float v = Xs[p][q * 32 + dd]; s += v * v; }
        Apart[q][p] = s;
    }
    __syncthreads();
    float maxn = wsb[WS_MAXN];
    if (tid < MT) {
        float s = 0.f;
        #pragma unroll
        for (int q = 0; q < 8; ++q) s += Apart[q][tid];
        Ash[tid] = s;
        Mls[tid] = 2.0f * (sqrtf(s) * maxn * 0.0078125f) + 1e-4f;  // 2*(2^-7 ||x|| wmax) + 2ulp slack
    }
    __syncthreads();

    // ---- hoist A-fragments (bf16) into registers: pt = wr*16 + (l&15), k = ks*32 + (l>>4)*8 ----
    bf16x8 af[8];
    {
        int pt = wr * 16 + (l & 15);
        #pragma unroll
        for (int ks = 0; ks < 8; ++ks) {
            int k0 = ks * 32 + (l >> 4) * 8;
            float4 u0 = *(const float4*)&Xs[pt][k0];
            float4 u1 = *(const float4*)&Xs[pt][k0 + 4];
            ABu t;
            t.h[0] = f2bf(u0.x); t.h[1] = f2bf(u0.y); t.h[2] = f2bf(u0.z); t.h[3] = f2bf(u0.w);
            t.h[4] = f2bf(u1.x); t.h[5] = f2bf(u1.y); t.h[6] = f2bf(u1.z); t.h[7] = f2bf(u1.w);
            af[ks] = t.v;
        }
    }

    f32x4 z = {0.f, 0.f, 0.f, 0.f};
    f32x4 acc0 = z, acc1 = z, acc2 = z, acc3 = z;

    int cst = tid >> 1;            // code 0..127 within chunk
    int seg = tid & 1;             // 16-d segment

    // prefetch round 0 (cc=0, dsub=0)
    float4 pr0, pr1, pr2, pr3;
    {
        const float* p = w + (size_t)cst * D + seg * 16;
        pr0 = *(const float4*)(p + 0);  pr1 = *(const float4*)(p + 4);
        pr2 = *(const float4*)(p + 8);  pr3 = *(const float4*)(p + 12);
    }

    // rounds: r = cc*8 + dsub ; chunk = [128 codes][32 d]
    for (int r = 0; r < 64; ++r) {
        __syncthreads();               // prev round's Wc reads done
        {   // commit prefetched fp32 -> bf16 granules
            ABu g0, g1;
            g0.h[0]=f2bf(pr0.x); g0.h[1]=f2bf(pr0.y); g0.h[2]=f2bf(pr0.z); g0.h[3]=f2bf(pr0.w);
            g0.h[4]=f2bf(pr1.x); g0.h[5]=f2bf(pr1.y); g0.h[6]=f2bf(pr1.z); g0.h[7]=f2bf(pr1.w);
            g1.h[0]=f2bf(pr2.x); g1.h[1]=f2bf(pr2.y); g1.h[2]=f2bf(pr2.z); g1.h[3]=f2bf(pr2.w);
            g1.h[4]=f2bf(pr3.x); g1.h[5]=f2bf(pr3.y); g1.h[6]=f2bf(pr3.z); g1.h[7]=f2bf(pr3.w);
            int base = ((cst >> 4) * 4) * 16 + (cst & 15);
            Wc[base + (seg * 2) * 16]     = g0.q;
            Wc[base + (seg * 2 + 1) * 16] = g1.q;
        }
        __syncthreads();               // Wc visible
        if (r + 1 < 64) {
            int cc = (r + 1) >> 3, ds = (r + 1) & 7;
            const float* p = w + (size_t)(cc * 128 + cst) * D + ds * 32 + seg * 16;
            pr0 = *(const float4*)(p + 0);  pr1 = *(const float4*)(p + 4);
            pr2 = *(const float4*)(p + 8);  pr3 = *(const float4*)(p + 12);
        }
        {   // 4 MFMAs: wave tile = 16 pts x 64 codes
            bf16x8 a = af[r & 7];
            int gb = (l >> 4) * 16 + (l & 15);
            bf16x8 b0 = *(const bf16x8*)&Wc[(wc * 4 + 0) * 64 + gb];
            bf16x8 b1 = *(const bf16x8*)&Wc[(wc * 4 + 1) * 64 + gb];
            bf16x8 b2 = *(const bf16x8*)&Wc[(wc * 4 + 2) * 64 + gb];
            bf16x8 b3 = *(const bf16x8*)&Wc[(wc * 4 + 3) * 64 + gb];
            acc0 = __builtin_amdgcn_mfma_f32_16x16x32_bf16(a, b0, acc0, 0, 0, 0);
            acc1 = __builtin_amdgcn_mfma_f32_16x16x32_bf16(a, b1, acc1, 0, 0, 0);
            acc2 = __builtin_amdgcn_mfma_f32_16x16x32_bf16(a, b2, acc2, 0, 0, 0);
            acc3 = __builtin_amdgcn_mfma_f32_16x16x32_bf16(a, b3, acc3, 0, 0, 0);
        }
        if ((r & 7) == 7) {            // code-chunk complete: fold into argmin state
            int cc = r >> 3;
            int kb = cc * 128 + wc * 64 + (l & 15);
            float dv0[4], dv1[4], dv2[4], dv3[4];
            #pragma unroll
            for (int g = 0; g < 4; ++g) {
                dv0[g] = Bs[kb +  0] - 2.0f * acc0[g];
                dv1[g] = Bs[kb + 16] - 2.0f * acc1[g];
                dv2[g] = Bs[kb + 32] - 2.0f * acc2[g];
                dv3[g] = Bs[kb + 48] - 2.0f * acc3[g];
            }
            #pragma unroll
            for (int g = 0; g < 4; ++g) {       // per-pt running min (C layout: row=(l>>4)*4+g)
                float m = fminf(fminf(dv0[g], dv1[g]), fminf(dv2[g], dv3[g]));
                m = fminf(m, __shfl_xor(m, 1, 64));
                m = fminf(m, __shfl_xor(m, 2, 64));
                m = fminf(m, __shfl_xor(m, 4, 64));
                m = fminf(m, __shfl_xor(m, 8, 64));
                int pt = wr * 16 + (l >> 4) * 4 + g;
                if ((l & 15) == 0) atomicMin(&runmin[pt], fenc(m));
            }
            if (cc == 0 && wv == 0) {           // stash tile(0,0) for the layout self-check
                #pragma unroll
                for (int g = 0; g < 4; ++g) chk[(l >> 4) * 4 + g][l & 15] = dv0[g];
            }
            __syncthreads();                    // all waves' mins in
            #pragma unroll
            for (int g = 0; g < 4; ++g) {
                int pt = wr * 16 + (l >> 4) * 4 + g;
                float thr = fdec(runmin[pt]) + Mls[pt];
                if (dv0[g] <= thr) { int s2 = atomicAdd(&cnt[pt], 1); if (s2 < 16) cand[pt][s2] = kb; }
                if (dv1[g] <= thr) { int s2 = atomicAdd(&cnt[pt], 1); if (s2 < 16) cand[pt][s2] = kb + 16; }
                if (dv2[g] <= thr) { int s2 = atomicAdd(&cnt[pt], 1); if (s2 < 16) cand[pt][s2] = kb + 32; }
                if (dv3[g] <= thr) { int s2 = atomicAdd(&cnt[pt], 1); if (s2 < 16) cand[pt][s2] = kb + 48; }
            }
            acc0 = z; acc1 = z; acc2 = z; acc3 = z;
        }
    }
    __syncthreads();

    // ---- layout self-check: tile(0,0) vs serial fp32; any error -> exact full scan ----
    if (tid < 64) {
        int pt = tid >> 2;
        bool bad = false;
        for (int jj = 0; jj < 4; ++jj) {
            int j = (tid & 3) + jj * 4;
            float cex = 0.f;
            for (int d0 = 0; d0 < D; d0 += 4) {
                float4 xv = *(const float4*)&Xs[pt][d0];
                float4 wv4 = *(const float4*)&w[(size_t)j * D + d0];
                cex = fmaf(xv.x, wv4.x, cex); cex = fmaf(xv.y, wv4.y, cex);
                cex = fmaf(xv.z, wv4.z, cex); cex = fmaf(xv.w, wv4.w, cex);
            }
            float sv = Bs[j] - 2.0f * cex;
            if (fabsf(sv - chk[pt][j]) > 0.02f) bad = true;
        }
        if (bad) atomicOr(&badflag, 1);
    }
    __syncthreads();

    // ---- exact phase: replicate R1's distance bit-for-bit on candidates ----
    if (tid < MT) {
        int p = tid;
        float a = Ash[p];
        float best = 3.4e38f; int bk = 0;
        bool full = (badflag != 0) || (cnt[p] > 16);
        if (!full) {
            int n = cnt[p];
            for (int i = 0; i < n; ++i) {
                int k = cand[p][i];
                float cex = 0.f;
                for (int d0 = 0; d0 < D; d0 += 4) {
                    float4 xv = *(const float4*)&Xs[p][d0];
                    float4 wv4 = *(const float4*)&w[(size_t)k * D + d0];
                    cex = fmaf(xv.x, wv4.x, cex); cex = fmaf(xv.y, wv4.y, cex);
                    cex = fmaf(xv.z, wv4.z, cex); cex = fmaf(xv.w, wv4.w, cex);
                }
                float t = a + Bs[k];
                float dvv = t - 2.0f * cex;
                if (dvv < best || (dvv == best && k < bk)) { best = dvv; bk = k; }
            }
        } else {
            for (int k = 0; k < K; ++k) {
                float cex = 0.f;
                for (int d0 = 0; d0 < D; d0 += 4) {
                    float4 xv = *(const float4*)&Xs[p][d0];
                    float4 wv4 = *(const float4*)&w[(size_t)k * D + d0];
                    cex = fmaf(xv.x, wv4.x, cex); cex = fmaf(xv.y, wv4.y, cex);
                    cex = fmaf(xv.z, wv4.z, cex); cex = fmaf(xv.w, wv4.w, cex);
                }
                float t = a + Bs[k];
                float dvv = t - 2.0f * cex;
                if (dvv < best) { best = dvv; bk = k; }   // ascending k: first-min
            }
        }
        out_idx[n0 + p] = (float)bk;
    }
}

// ---------------- kernel 3: gather + out + commitment/codebook SSE ----------------
__global__ __launch_bounds__(256) void gather_kernel(const float* __restrict__ x,
                                                     const float* __restrict__ w,
                                                     const float* __restrict__ idxf,
                                                     float* __restrict__ out,
                                                     float* __restrict__ ws) {
    __shared__ float red[256];
    int tid = threadIdx.x;
    size_t t0 = (size_t)blockIdx.x * 256 + tid;
    const size_t total4 = OUT_ELEMS / 4;
    const size_t stride = (size_t)2048 * 256;

    float sse = 0.f;
    for (size_t e4 = t0; e4 < total4; e4 += stride) {
        size_t e = e4 * 4;
        int b  = (int)(e >> 18);
        int c  = (int)((e >> 10) & 255);
        int hw = (int)(e & 1023);
        int n  = (b << 10) + hw;
        (void)hw;

        float4 xv = *(const float4*)(x + e);
        int k0 = (int)idxf[n + 0];
        int k1 = (int)idxf[n + 1];
        int k2 = (int)idxf[n + 2];
        int k3 = (int)idxf[n + 3];
        float w0 = w[(size_t)k0 * D + c];
        float w1 = w[(size_t)k1 * D + c];
        float w2 = w[(size_t)k2 * D + c];
        float w3 = w[(size_t)k3 * D + c];
        float d0 = w0 - xv.x, d1 = w1 - xv.y, d2 = w2 - xv.z, d3 = w3 - xv.w;
        float4 ov;
        ov.x = xv.x + d0;  ov.y = xv.y + d1;
        ov.z = xv.z + d2;  ov.w = xv.w + d3;
        *(float4*)(out + e) = ov;
        sse += d0 * d0 + d1 * d1 + d2 * d2 + d3 * d3;
    }

    red[tid] = sse;
    __syncthreads();
    for (int s = 128; s > 0; s >>= 1) {
        if (tid < s) red[tid] += red[tid + s];
        __syncthreads();
    }
    if (tid == 0) atomicAdd(ws + WS_SSE_VQ, red[0]);
}

// ---------------- kernel 4: orthogonality regularizer ----------------
__global__ __launch_bounds__(256) void ortho_kernel(const float* __restrict__ w,
                                                    float* __restrict__ ws) {
    __shared__ float wi[D];
    __shared__ float wsum[4];
    int i = blockIdx.x;
    int tid = threadIdx.x;
    int lane = tid & 63;
    int wid = tid >> 6;

    if (tid < 64)
        *(float4*)&wi[tid * 4] = *(const float4*)(w + (size_t)i * D + tid * 4);
    __syncthreads();

    float inv_i = 1.0f / ws[WS_NORM + i];
    float acc = 0.f;
    for (int j = wid; j < K; j += 4) {
        float4 a = *(const float4*)(w + (size_t)j * D + lane * 4);
        float4 bq = *(const float4*)&wi[lane * 4];
        float s = a.x * bq.x + a.y * bq.y + a.z * bq.z + a.w * bq.w;
        for (int m = 32; m; m >>= 1) s += __shfl_xor(s, m, 64);
        float sij = s * inv_i * (1.0f / ws[WS_NORM + j]);
        float t = sij - (j == i ? 1.0f : 0.0f);
        acc += t * t;
    }
    if (lane == 0) wsum[wid] = acc;
    __syncthreads();
    if (tid == 0)
        atomicAdd(ws + WS_SSE_ORTHO, wsum[0] + wsum[1] + wsum[2] + wsum[3]);
}

// ---------------- kernel 5: finalize loss ----------------
__global__ void finalize_kernel(const float* __restrict__ ws, float* __restrict__ out) {
    float loss = (1.0f + BETA) * ws[WS_SSE_VQ] / (float)OUT_ELEMS
               + ORTHO_L * sqrtf(ws[WS_SSE_ORTHO]) / ((float)K * (float)K);
    out[LOSS_OFF] = loss;
}

extern "C" void kernel_launch(void* const* d_in, const int* in_sizes, int n_in,
                              void* d_out, int out_size, void* d_ws, size_t ws_size,
                              hipStream_t stream) {
    const float* x = (const float*)d_in[0];
    const float* w = (const float*)d_in[1];
    float* out = (float*)d_out;
    float* ws  = (float*)d_ws;

    hipMemsetAsync(d_ws, 0, 4 * sizeof(float), stream);
    codes_kernel<<<K, 64, 0, stream>>>(w, ws);
    argmin_kernel<<<N_PTS / MT, 256, 0, stream>>>(x, w, ws, out + IDX_OFF);
    ortho_kernel<<<K, 256, 0, stream>>>(w, ws);
    gather_kernel<<<2048, 256, 0, stream>>>(x, w, out + IDX_OFF, out, ws);
    finalize_kernel<<<1, 1, 0, stream>>>(ws, out);
}

// Round 9
// 1434.537 us; speedup vs baseline: 2.0376x; 2.0376x over previous
//
#include <hip/hip_runtime.h>
#include <math.h>

#define D 256
#define K 1024
#define N_PTS 65536            // 64 * 32 * 32
#define BETA 0.25f
#define ORTHO_L 10.0f

#define OUT_ELEMS 16777216     // 64*256*32*32
#define LOSS_OFF 16777216
#define IDX_OFF  16777217

// ws float layout
#define WS_SSE_VQ    0
#define WS_SSE_ORTHO 1
#define WS_MAXN      2            // max ||e_k|| as float bits (atomicMax on uint)
#define WS_B         4            // 1024 floats: ||e_k||^2
#define WS_NORM      (4 + 1024)   // 1024 floats: ||e_k||

typedef short bf16x8 __attribute__((ext_vector_type(8)));
typedef float f32x4  __attribute__((ext_vector_type(4)));

union ABu { bf16x8 v; unsigned short h[8]; uint4 q; };

__device__ __forceinline__ unsigned short f2bf(float v) {
    unsigned u = __float_as_uint(v);
    unsigned r = (u + 0x7FFFu + ((u >> 16) & 1u)) >> 16;   // RNE
    return (unsigned short)r;
}
// monotone float<->uint keys for min over possibly-negative floats
__device__ __forceinline__ unsigned fenc(float f) {
    unsigned b = __float_as_uint(f);
    return (b & 0x80000000u) ? ~b : (b | 0x80000000u);
}
__device__ __forceinline__ float fdec(unsigned e) {
    unsigned b = (e & 0x80000000u) ? (e & 0x7FFFFFFFu) : ~e;
    return __uint_as_float(b);
}

// ---------------- kernel 1: per-code squared norms (+ max norm) ----------------
__global__ __launch_bounds__(64) void codes_kernel(const float* __restrict__ w,
                                                   float* __restrict__ ws) {
    int k = blockIdx.x;
    int lane = threadIdx.x;                       // 0..63
    float4 v = *(const float4*)(w + (size_t)k * D + lane * 4);
    float s = v.x * v.x + v.y * v.y + v.z * v.z + v.w * v.w;
    for (int m = 32; m; m >>= 1) s += __shfl_xor(s, m, 64);
    if (lane == 0) {
        float nrm = sqrtf(s);
        ws[WS_B + k] = s;
        ws[WS_NORM + k] = nrm;
        atomicMax((unsigned*)(ws + WS_MAXN), __float_as_uint(nrm));  // positive floats
    }
}

// ---------------- kernel 2: MFMA filter + exact-fp32 rescue argmin ----------------
// Phase A: approx scores via mfma_f32_16x16x32_bf16, running min + candidates
//          (cap 32/pt; mean ~5; P(overflow) ~ 0).
// Phase B: layout self-check (tile(0,0) vs serial fp32).
// Phase C: exact R1-replica distances on candidates, parallel across all 256
//          threads, first-min via packed (fenc(dv)<<32|k) LDS atomicMin64.
//          Overflow/badflag -> WAVE-parallel full scan (~12us, no ms cliff).
#define MT 32
#define CAND_CAP 32

__global__ __launch_bounds__(256) void argmin_kernel(const float* __restrict__ x,
                                                     const float* __restrict__ w,
                                                     const float* __restrict__ wsb,
                                                     float* __restrict__ out_idx) {
    __shared__ float Xs[MT][260];     // fp32 X, pt-major, pad 260 (33.3 KB, 4-way on exact path)
    __shared__ uint4 Wc[512];         // bf16 W chunk [128 codes][32 d] as 16B granules (8 KB)
    __shared__ float Bs[K];           // 4 KB
    __shared__ float Apart[8][MT];
    __shared__ float Ash[MT];
    __shared__ float Mls[MT];
    __shared__ unsigned runmin[MT];
    __shared__ int cnt[MT];
    __shared__ int cand[MT][CAND_CAP];   // 4 KB
    __shared__ unsigned long long amin[MT];
    __shared__ int ovf[MT];
    __shared__ float chk[16][16];
    __shared__ int badflag;

    int tid = threadIdx.x;
    int l   = tid & 63;
    int wv  = tid >> 6;
    int wr  = wv >> 1;
    int wc  = wv & 1;

    int n0 = blockIdx.x * MT;
    int b  = n0 >> 10;
    int hw0 = n0 & 1023;

    // ---- stage X fp32 (pt-major) ----
    const float* xb = x + (size_t)b * (D * 1024) + hw0;
    {
        int p = tid & 31, cq = tid >> 5;
        for (int c0 = 0; c0 < D; c0 += 8) {
            int c = c0 + cq;
            Xs[p][c] = xb[(size_t)c * 1024 + p];
        }
    }
    *(float4*)&Bs[tid * 4] = *(const float4*)&wsb[WS_B + tid * 4];
    if (tid < MT) {
        runmin[tid] = 0xFFFFFFFFu; cnt[tid] = 0;
        amin[tid] = 0xFFFFFFFFFFFFFFFFull;
    }
    if (tid == 0) badflag = 0;
    __syncthreads();

    // ---- A_n exact (same tree as R1: 32-chunk sums, then q-ascending) ----
    {
        int p = tid & 31, q = tid >> 5;
        float s = 0.f;
        #pragma unroll
        for (int dd = 0; dd < 32; ++dd) { float v = Xs[p][q * 32 + dd]; s += v * v; }
        Apart[q][p] = s;
    }
    __syncthreads();
    float maxn = wsb[WS_MAXN];
    if (tid < MT) {
        float s = 0.f;
        #pragma unroll
        for (int q = 0; q < 8; ++q) s += Apart[q][tid];
        Ash[tid] = s;
        Mls[tid] = 2.0f * (sqrtf(s) * maxn * 0.0078125f) + 1e-4f;  // 2*(2^-7 ||x|| wmax) + slack
    }
    __syncthreads();

    // ---- hoist A-fragments (bf16): pt = wr*16 + (l&15), k = ks*32 + (l>>4)*8 ----
    bf16x8 af[8];
    {
        int pt = wr * 16 + (l & 15);
        #pragma unroll
        for (int ks = 0; ks < 8; ++ks) {
            int k0 = ks * 32 + (l >> 4) * 8;
            float4 u0 = *(const float4*)&Xs[pt][k0];
            float4 u1 = *(const float4*)&Xs[pt][k0 + 4];
            ABu t;
            t.h[0] = f2bf(u0.x); t.h[1] = f2bf(u0.y); t.h[2] = f2bf(u0.z); t.h[3] = f2bf(u0.w);
            t.h[4] = f2bf(u1.x); t.h[5] = f2bf(u1.y); t.h[6] = f2bf(u1.z); t.h[7] = f2bf(u1.w);
            af[ks] = t.v;
        }
    }

    f32x4 z = {0.f, 0.f, 0.f, 0.f};
    f32x4 acc0 = z, acc1 = z, acc2 = z, acc3 = z;

    int cst = tid >> 1;            // code 0..127 within chunk
    int seg = tid & 1;             // 16-d segment

    float4 pr0, pr1, pr2, pr3;
    {
        const float* p = w + (size_t)cst * D + seg * 16;
        pr0 = *(const float4*)(p + 0);  pr1 = *(const float4*)(p + 4);
        pr2 = *(const float4*)(p + 8);  pr3 = *(const float4*)(p + 12);
    }

    for (int r = 0; r < 64; ++r) {
        __syncthreads();               // prev round's Wc reads done
        {   // commit prefetched fp32 -> bf16 granules
            ABu g0, g1;
            g0.h[0]=f2bf(pr0.x); g0.h[1]=f2bf(pr0.y); g0.h[2]=f2bf(pr0.z); g0.h[3]=f2bf(pr0.w);
            g0.h[4]=f2bf(pr1.x); g0.h[5]=f2bf(pr1.y); g0.h[6]=f2bf(pr1.z); g0.h[7]=f2bf(pr1.w);
            g1.h[0]=f2bf(pr2.x); g1.h[1]=f2bf(pr2.y); g1.h[2]=f2bf(pr2.z); g1.h[3]=f2bf(pr2.w);
            g1.h[4]=f2bf(pr3.x); g1.h[5]=f2bf(pr3.y); g1.h[6]=f2bf(pr3.z); g1.h[7]=f2bf(pr3.w);
            int base = ((cst >> 4) * 4) * 16 + (cst & 15);
            Wc[base + (seg * 2) * 16]     = g0.q;
            Wc[base + (seg * 2 + 1) * 16] = g1.q;
        }
        __syncthreads();               // Wc visible
        if (r + 1 < 64) {
            int cc = (r + 1) >> 3, ds = (r + 1) & 7;
            const float* p = w + (size_t)(cc * 128 + cst) * D + ds * 32 + seg * 16;
            pr0 = *(const float4*)(p + 0);  pr1 = *(const float4*)(p + 4);
            pr2 = *(const float4*)(p + 8);  pr3 = *(const float4*)(p + 12);
        }
        {   // 4 MFMAs: wave tile = 16 pts x 64 codes
            bf16x8 a = af[r & 7];
            int gb = (l >> 4) * 16 + (l & 15);
            bf16x8 b0 = *(const bf16x8*)&Wc[(wc * 4 + 0) * 64 + gb];
            bf16x8 b1 = *(const bf16x8*)&Wc[(wc * 4 + 1) * 64 + gb];
            bf16x8 b2 = *(const bf16x8*)&Wc[(wc * 4 + 2) * 64 + gb];
            bf16x8 b3 = *(const bf16x8*)&Wc[(wc * 4 + 3) * 64 + gb];
            acc0 = __builtin_amdgcn_mfma_f32_16x16x32_bf16(a, b0, acc0, 0, 0, 0);
            acc1 = __builtin_amdgcn_mfma_f32_16x16x32_bf16(a, b1, acc1, 0, 0, 0);
            acc2 = __builtin_amdgcn_mfma_f32_16x16x32_bf16(a, b2, acc2, 0, 0, 0);
            acc3 = __builtin_amdgcn_mfma_f32_16x16x32_bf16(a, b3, acc3, 0, 0, 0);
        }
        if ((r & 7) == 7) {            // code-chunk complete: fold into argmin state
            int cc = r >> 3;
            int kb = cc * 128 + wc * 64 + (l & 15);
            float dv0[4], dv1[4], dv2[4], dv3[4];
            #pragma unroll
            for (int g = 0; g < 4; ++g) {
                dv0[g] = Bs[kb +  0] - 2.0f * acc0[g];
                dv1[g] = Bs[kb + 16] - 2.0f * acc1[g];
                dv2[g] = Bs[kb + 32] - 2.0f * acc2[g];
                dv3[g] = Bs[kb + 48] - 2.0f * acc3[g];
            }
            #pragma unroll
            for (int g = 0; g < 4; ++g) {       // per-pt running min (C: row=(l>>4)*4+g, col=l&15)
                float m = fminf(fminf(dv0[g], dv1[g]), fminf(dv2[g], dv3[g]));
                m = fminf(m, __shfl_xor(m, 1, 64));
                m = fminf(m, __shfl_xor(m, 2, 64));
                m = fminf(m, __shfl_xor(m, 4, 64));
                m = fminf(m, __shfl_xor(m, 8, 64));
                int pt = wr * 16 + (l >> 4) * 4 + g;
                if ((l & 15) == 0) atomicMin(&runmin[pt], fenc(m));
            }
            if (cc == 0 && wv == 0) {           // stash tile(0,0) for the layout self-check
                #pragma unroll
                for (int g = 0; g < 4; ++g) chk[(l >> 4) * 4 + g][l & 15] = dv0[g];
            }
            __syncthreads();                    // all waves' mins in
            #pragma unroll
            for (int g = 0; g < 4; ++g) {
                int pt = wr * 16 + (l >> 4) * 4 + g;
                float thr = fdec(runmin[pt]) + Mls[pt];
                if (dv0[g] <= thr) { int s2 = atomicAdd(&cnt[pt], 1); if (s2 < CAND_CAP) cand[pt][s2] = kb; }
                if (dv1[g] <= thr) { int s2 = atomicAdd(&cnt[pt], 1); if (s2 < CAND_CAP) cand[pt][s2] = kb + 16; }
                if (dv2[g] <= thr) { int s2 = atomicAdd(&cnt[pt], 1); if (s2 < CAND_CAP) cand[pt][s2] = kb + 32; }
                if (dv3[g] <= thr) { int s2 = atomicAdd(&cnt[pt], 1); if (s2 < CAND_CAP) cand[pt][s2] = kb + 48; }
            }
            acc0 = z; acc1 = z; acc2 = z; acc3 = z;
        }
    }
    __syncthreads();

    // ---- layout self-check: tile(0,0) vs serial fp32 ----
    if (tid < 64) {
        int pt = tid >> 2;
        bool bad = false;
        for (int jj = 0; jj < 4; ++jj) {
            int j = (tid & 3) + jj * 4;
            float cex = 0.f;
            for (int d0 = 0; d0 < D; d0 += 4) {
                float4 xv = *(const float4*)&Xs[pt][d0];
                float4 wv4 = *(const float4*)&w[(size_t)j * D + d0];
                cex = fmaf(xv.x, wv4.x, cex); cex = fmaf(xv.y, wv4.y, cex);
                cex = fmaf(xv.z, wv4.z, cex); cex = fmaf(xv.w, wv4.w, cex);
            }
            float sv = Bs[j] - 2.0f * cex;
            if (fabsf(sv - chk[pt][j]) > 0.02f) bad = true;
        }
        if (bad) atomicOr(&badflag, 1);
    }
    __syncthreads();
    if (tid < MT) ovf[tid] = (badflag != 0) || (cnt[tid] > CAND_CAP);
    __syncthreads();

    // ---- exact phase 1: candidates, parallel across all 256 threads ----
    // exact tree identical to R1/R7 (fmaf ascending d0; fl(A+B) - fl(2C));
    // first-min tie-break via packed key (smaller dv, then smaller k).
    for (int e = tid; e < MT * CAND_CAP; e += 256) {
        int p = e >> 5, ci = e & (CAND_CAP - 1);
        if (!ovf[p] && ci < cnt[p]) {
            int k = cand[p][ci];
            float cex = 0.f;
            const float* xrow = &Xs[p][0];
            const float* wrow = w + (size_t)k * D;
            for (int d0 = 0; d0 < D; d0 += 4) {
                float4 xv = *(const float4*)(xrow + d0);
                float4 wv4 = *(const float4*)(wrow + d0);
                cex = fmaf(xv.x, wv4.x, cex); cex = fmaf(xv.y, wv4.y, cex);
                cex = fmaf(xv.z, wv4.z, cex); cex = fmaf(xv.w, wv4.w, cex);
            }
            float t = Ash[p] + Bs[k];
            float dv = t - 2.0f * cex;
            unsigned long long key = ((unsigned long long)fenc(dv) << 32) | (unsigned)k;
            atomicMin(&amin[p], key);
        }
    }

    // ---- exact phase 2: overflow/badflag -> wave-parallel full scan (graceful) ----
    for (int p = wv; p < MT; p += 4) {
        if (ovf[p]) {
            unsigned long long best = 0xFFFFFFFFFFFFFFFFull;
            const float* xrow = &Xs[p][0];
            for (int kk = 0; kk < 16; ++kk) {
                int k = l * 16 + kk;
                float cex = 0.f;
                const float* wrow = w + (size_t)k * D;
                for (int d0 = 0; d0 < D; d0 += 4) {
                    float4 xv = *(const float4*)(xrow + d0);
                    float4 wv4 = *(const float4*)(wrow + d0);
                    cex = fmaf(xv.x, wv4.x, cex); cex = fmaf(xv.y, wv4.y, cex);
                    cex = fmaf(xv.z, wv4.z, cex); cex = fmaf(xv.w, wv4.w, cex);
                }
                float t = Ash[p] + Bs[k];
                float dv = t - 2.0f * cex;
                unsigned long long key = ((unsigned long long)fenc(dv) << 32) | (unsigned)k;
                if (key < best) best = key;
            }
            for (int m = 32; m; m >>= 1) {
                unsigned long long o = ((unsigned long long)__shfl_xor((int)(best >> 32), m, 64) << 32)
                                     | (unsigned)__shfl_xor((int)(best & 0xFFFFFFFFull), m, 64);
                if (o < best) best = o;
            }
            if (l == 0) atomicMin(&amin[p], best);
        }
    }
    __syncthreads();

    if (tid < MT)
        out_idx[n0 + tid] = (float)(int)(amin[tid] & 0xFFFFFFFFull);
}

// ---------------- kernel 3: gather + out + commitment/codebook SSE ----------------
__global__ __launch_bounds__(256) void gather_kernel(const float* __restrict__ x,
                                                     const float* __restrict__ w,
                                                     const float* __restrict__ idxf,
                                                     float* __restrict__ out,
                                                     float* __restrict__ ws) {
    __shared__ float red[256];
    int tid = threadIdx.x;
    size_t t0 = (size_t)blockIdx.x * 256 + tid;
    const size_t total4 = OUT_ELEMS / 4;
    const size_t stride = (size_t)2048 * 256;

    float sse = 0.f;
    for (size_t e4 = t0; e4 < total4; e4 += stride) {
        size_t e = e4 * 4;
        int b  = (int)(e >> 18);
        int c  = (int)((e >> 10) & 255);
        int hw = (int)(e & 1023);
        int n  = (b << 10) + hw;

        float4 xv = *(const float4*)(x + e);
        int k0 = (int)idxf[n + 0];
        int k1 = (int)idxf[n + 1];
        int k2 = (int)idxf[n + 2];
        int k3 = (int)idxf[n + 3];
        float w0 = w[(size_t)k0 * D + c];
        float w1 = w[(size_t)k1 * D + c];
        float w2 = w[(size_t)k2 * D + c];
        float w3 = w[(size_t)k3 * D + c];
        float d0 = w0 - xv.x, d1 = w1 - xv.y, d2 = w2 - xv.z, d3 = w3 - xv.w;
        float4 ov;
        ov.x = xv.x + d0;  ov.y = xv.y + d1;
        ov.z = xv.z + d2;  ov.w = xv.w + d3;
        *(float4*)(out + e) = ov;
        sse += d0 * d0 + d1 * d1 + d2 * d2 + d3 * d3;
    }

    red[tid] = sse;
    __syncthreads();
    for (int s = 128; s > 0; s >>= 1) {
        if (tid < s) red[tid] += red[tid + s];
        __syncthreads();
    }
    if (tid == 0) atomicAdd(ws + WS_SSE_VQ, red[0]);
}

// ---------------- kernel 4: orthogonality regularizer ----------------
__global__ __launch_bounds__(256) void ortho_kernel(const float* __restrict__ w,
                                                    float* __restrict__ ws) {
    __shared__ float wi[D];
    __shared__ float wsum[4];
    int i = blockIdx.x;
    int tid = threadIdx.x;
    int lane = tid & 63;
    int wid = tid >> 6;

    if (tid < 64)
        *(float4*)&wi[tid * 4] = *(const float4*)(w + (size_t)i * D + tid * 4);
    __syncthreads();

    float inv_i = 1.0f / ws[WS_NORM + i];
    float acc = 0.f;
    for (int j = wid; j < K; j += 4) {
        float4 a = *(const float4*)(w + (size_t)j * D + lane * 4);
        float4 bq = *(const float4*)&wi[lane * 4];
        float s = a.x * bq.x + a.y * bq.y + a.z * bq.z + a.w * bq.w;
        for (int m = 32; m; m >>= 1) s += __shfl_xor(s, m, 64);
        float sij = s * inv_i * (1.0f / ws[WS_NORM + j]);
        float t = sij - (j == i ? 1.0f : 0.0f);
        acc += t * t;
    }
    if (lane == 0) wsum[wid] = acc;
    __syncthreads();
    if (tid == 0)
        atomicAdd(ws + WS_SSE_ORTHO, wsum[0] + wsum[1] + wsum[2] + wsum[3]);
}

// ---------------- kernel 5: finalize loss ----------------
__global__ void finalize_kernel(const float* __restrict__ ws, float* __restrict__ out) {
    float loss = (1.0f + BETA) * ws[WS_SSE_VQ] / (float)OUT_ELEMS
               + ORTHO_L * sqrtf(ws[WS_SSE_ORTHO]) / ((float)K * (float)K);
    out[LOSS_OFF] = loss;
}

extern "C" void kernel_launch(void* const* d_in, const int* in_sizes, int n_in,
                              void* d_out, int out_size, void* d_ws, size_t ws_size,
                              hipStream_t stream) {
    const float* x = (const float*)d_in[0];
    const float* w = (const float*)d_in[1];
    float* out = (float*)d_out;
    float* ws  = (float*)d_ws;

    hipMemsetAsync(d_ws, 0, 4 * sizeof(float), stream);
    codes_kernel<<<K, 64, 0, stream>>>(w, ws);
    argmin_kernel<<<N_PTS / MT, 256, 0, stream>>>(x, w, ws, out + IDX_OFF);
    ortho_kernel<<<K, 256, 0, stream>>>(w, ws);
    gather_kernel<<<2048, 256, 0, stream>>>(x, w, out + IDX_OFF, out, ws);
    finalize_kernel<<<1, 1, 0, stream>>>(ws, out);
}